// Round 6
// baseline (64.669 us; speedup 1.0000x reference)
//
#include <hip/hip_runtime.h>

// CurveGraphic2d: 16 cubic Beziers rendered onto 256x256 canvases (fp32).
// Per batch: 64 arc-length-uniform samples; per pixel:
// min distance to samples -> (d/w + eps)^aa -> clip(1 - ., 0, 1).
//
// Dtype: fp32 in / fp32 out (R2-vs-R3 differential established this).
// Structure: LDS-only sampling pipeline (no wave shuffles — R1/R4 with
// __shfl scan/search both produced blank canvases; LDS rounds R3/R5 passed).
//
// R6 deltas vs R5 (all conservative, math forms identical to R5):
//  - phase1+2a merged: tid<63 evaluates bezier at t_tid AND t_{tid+1}
//    (bit-identical to neighbor's value) -> seg directly; one less barrier.
//  - phase3 search: 64 independent pipelined LDS reads (count-scan) instead
//    of 6 dependent reads; same "cum[j]*invT <= t0" comparison as R5.
//  - render: 8 px/lane (dy^2 shared across 8 fma/fmin), 2 rows/wave,
//    512 blocks -> half the redundant per-block sampling work.

#define EPSILON 1e-6f
#define NS 64

__device__ __forceinline__ void bezier4(const float cy[4], const float cx[4],
                                        float t, float& ry, float& rx) {
    float s = 1.0f - t;
    float ay0 = s * cy[0] + t * cy[1];
    float ay1 = s * cy[1] + t * cy[2];
    float ay2 = s * cy[2] + t * cy[3];
    float by0 = s * ay0 + t * ay1;
    float by1 = s * ay1 + t * ay2;
    ry = s * by0 + t * by1;
    float ax0 = s * cx[0] + t * cx[1];
    float ax1 = s * cx[1] + t * cx[2];
    float ax2 = s * cx[2] + t * cx[3];
    float bx0 = s * ax0 + t * ax1;
    float bx1 = s * ax1 + t * ax2;
    rx = s * bx0 + t * bx1;
}

__global__ __launch_bounds__(256) void curve_kernel(
    const float* __restrict__ inputs,   // [16,4,2] (y,x) in [0,1]
    const float* __restrict__ widths,   // [16]
    const float* __restrict__ aas,      // [16]
    float* __restrict__ out)            // [16,256,256]
{
    __shared__ float s_seg[NS];            // segment lengths (63 used)
    __shared__ float s_cum[NS];            // cumulative arc length
    __shared__ float s_total;
    __shared__ float2 s_pts[NS];           // final sample points (y,x)

    const int b       = blockIdx.x >> 5;         // 32 blocks per batch
    const int rowbase = (blockIdx.x & 31) << 3;  // 8 rows per block
    const int tid     = threadIdx.x;

    // ---- phase 1: segment lengths directly (merged pts0 + diff) ----
    float cy[4], cx[4];
    if (tid < NS) {
        #pragma unroll
        for (int i = 0; i < 4; ++i) {
            cy[i] = inputs[b * 8 + 2 * i + 0] * 256.0f;
            cx[i] = inputs[b * 8 + 2 * i + 1] * 256.0f;
        }
        if (tid < NS - 1) {
            float py, px, qy, qx;
            bezier4(cy, cx, (float)tid / 63.0f, py, px);
            bezier4(cy, cx, (float)(tid + 1) / 63.0f, qy, qx);
            float dy = qy - py, dx = qx - px;
            s_seg[tid] = sqrtf(dy * dy + dx * dx);
        }
    }
    __syncthreads();

    // ---- phase 2: serial cumsum, register chain (jnp.cumsum order) ----
    if (tid == 0) {
        float c = 0.0f;
        s_cum[0] = 0.0f;
        #pragma unroll
        for (int l = 1; l < NS; ++l) {      // pipelined independent reads,
            c += s_seg[l - 1];              // dependent chain = adds only
            s_cum[l] = c;
        }
        s_total = c;
    }
    __syncthreads();

    // ---- phase 3: t_arc = np.interp(t0, u, ts0), resample ----
    if (tid < NS) {
        const float t0   = (float)tid / 63.0f;
        const float invT = 1.0f / (s_total + EPSILON);
        // largest j with u[j] <= t0, u[j] = cum[j]*invT (u[0]=0, increasing).
        // count-scan: 64 independent LDS reads, fully pipelined.
        int cnt = 0;
        #pragma unroll
        for (int j = 0; j < NS; ++j)
            cnt += (s_cum[j] * invT <= t0) ? 1 : 0;
        int lo = cnt - 1;                     // cum[0]=0 <= t0 -> cnt >= 1
        float t_arc;
        if (lo >= 63) {
            t_arc = 1.0f;                     // query beyond u[-1] -> ts0[-1]
        } else {
            float uj    = s_cum[lo] * invT;
            float uj1   = s_cum[lo + 1] * invT;
            float denom = uj1 - uj;
            float tsj   = (float)lo / 63.0f;
            t_arc = (denom > 0.0f)
                  ? tsj + (t0 - uj) / denom * (1.0f / 63.0f)
                  : tsj;
        }
        float sy, sx;
        bezier4(cy, cx, t_arc, sy, sx);
        s_pts[tid] = make_float2(sy, sx);
    }
    __syncthreads();

    // ---- phase 4: render 2 rows per wave, 8 px per lane ----
    const float w    = widths[b];
    const float aa   = aas[b];
    const float invw = 1.0f / w;

    const int wave = tid >> 6;
    const int lane = tid & 63;
    const int row  = rowbase + (wave << 1) + (lane >> 5);
    const float pyf = (float)row;
    const float px0 = (float)((lane & 31) << 3);

    float m[8];
    #pragma unroll
    for (int k = 0; k < 8; ++k) m[k] = 1e30f;

    #pragma unroll 8
    for (int i = 0; i < NS; ++i) {
        float2 sp = s_pts[i];                  // 2-way LDS alias: free (m136)
        float dy  = sp.x - pyf;
        float dy2 = dy * dy;
        float dx  = sp.y - px0;
        #pragma unroll
        for (int k = 0; k < 8; ++k) {
            float d = fmaf(dx, dx, dy2);
            m[k] = fminf(m[k], d);
            dx -= 1.0f;
        }
    }

    float vv[8];
    #pragma unroll
    for (int k = 0; k < 8; ++k) {
        float md = sqrtf(m[k]);                // sqrt(min d^2) == min d
        float c  = md * invw + EPSILON;
        float v  = 1.0f - exp2f(aa * log2f(c)); // c^aa, c >= 1e-6 > 0
        vv[k] = fminf(fmaxf(v, 0.0f), 1.0f);
    }

    const int base = (b << 16) | (row << 8) | ((lane & 31) << 3); // elem idx
    float4* o4 = reinterpret_cast<float4*>(out);
    o4[(base >> 2) + 0] = make_float4(vv[0], vv[1], vv[2], vv[3]);
    o4[(base >> 2) + 1] = make_float4(vv[4], vv[5], vv[6], vv[7]);
}

extern "C" void kernel_launch(void* const* d_in, const int* in_sizes, int n_in,
                              void* d_out, int out_size, void* d_ws, size_t ws_size,
                              hipStream_t stream) {
    const float* inp = (const float*)d_in[0];
    const float* wid = (const float*)d_in[1];
    const float* aaf = (const float*)d_in[2];
    float* out = (float*)d_out;

    dim3 grid(16 * 32);   // 16 batches x 32 blocks (8 rows each)
    dim3 block(256);
    hipLaunchKernelGGL(curve_kernel, grid, block, 0, stream,
                       inp, wid, aaf, out);
}